// Round 1
// baseline (236.455 us; speedup 1.0000x reference)
//
#include <hip/hip_runtime.h>
#include <math.h>

// CPHASE on qubits (0,1) of a 22-qubit state, batch B=4 (innermost axis).
// state flat index: (((q0*2+q1) * 2^20 + rest) * 4 + b), so q01 = idx >> 22.
// Only q01 == 3 gets the phase exp(i*theta[b]); rest is a pass-through copy.
// out = [re block (2^24 floats)][im block (2^24 floats)].

#define N_ELEMS (1u << 24)          // 2^22 amplitudes * 4 batch
#define N_VEC   (N_ELEMS / 4u)      // float4 per thread
#define PHASE_START (3u << 20)      // first float4 index with q01==3

__global__ __launch_bounds__(256)
void CPHASE_34583076667990_kernel(const float4* __restrict__ re_in,
                                  const float4* __restrict__ im_in,
                                  const float*  __restrict__ theta,
                                  float4* __restrict__ out_re,
                                  float4* __restrict__ out_im) {
    unsigned t = blockIdx.x * blockDim.x + threadIdx.x;  // [0, N_VEC)
    float4 re = re_in[t];
    float4 im = im_in[t];
    if (t >= PHASE_START) {
        // one float4 = batch lanes b=0..3 of a single amplitude
        float s0, c0, s1, c1, s2, c2, s3, c3;
        sincosf(theta[0], &s0, &c0);
        sincosf(theta[1], &s1, &c1);
        sincosf(theta[2], &s2, &c2);
        sincosf(theta[3], &s3, &c3);
        float4 nre, nim;
        nre.x = re.x * c0 - im.x * s0;  nim.x = re.x * s0 + im.x * c0;
        nre.y = re.y * c1 - im.y * s1;  nim.y = re.y * s1 + im.y * c1;
        nre.z = re.z * c2 - im.z * s2;  nim.z = re.z * s2 + im.z * c2;
        nre.w = re.w * c3 - im.w * s3;  nim.w = re.w * s3 + im.w * c3;
        re = nre;
        im = nim;
    }
    out_re[t] = re;
    out_im[t] = im;
}

extern "C" void kernel_launch(void* const* d_in, const int* in_sizes, int n_in,
                              void* d_out, int out_size, void* d_ws, size_t ws_size,
                              hipStream_t stream) {
    const float* re    = (const float*)d_in[0];
    const float* im    = (const float*)d_in[1];
    const float* theta = (const float*)d_in[2];
    float* out = (float*)d_out;

    dim3 block(256);
    dim3 grid(N_VEC / 256);  // 2^22 / 256 = 16384 blocks
    CPHASE_34583076667990_kernel<<<grid, block, 0, stream>>>(
        (const float4*)re, (const float4*)im, theta,
        (float4*)out, (float4*)(out + N_ELEMS));
}

// Round 3
// 225.534 us; speedup vs baseline: 1.0484x; 1.0484x over previous
//
#include <hip/hip_runtime.h>
#include <math.h>

// CPHASE on qubits (0,1) of a 22-qubit state, batch B=4 (innermost axis).
// Flat amplitude index: (((q0*2+q1) * 2^20 + rest) * 4 + b)  -> q01 = top 2 bits.
// Only the q01==3 quarter gets phase exp(i*theta[b]); the rest is a copy.
// Phase factors are batch-constant (8 floats) -> precompute into d_ws with a
// tiny setup kernel so the streaming kernel has zero transcendentals.
//
// Use clang native vectors (ext_vector_type) — HIP's float4 class is not
// accepted by __builtin_nontemporal_load/store.

typedef float v4f __attribute__((ext_vector_type(4)));

#define N_ELEMS (1u << 24)          // 2^22 amplitudes * 4 batch
#define N_VEC   (N_ELEMS / 4u)      // one v4f (all 4 batch lanes) per thread
#define PHASE_START (3u << 20)      // first v4f index with q01==3

__global__ __launch_bounds__(64)
void cphase_setup(const float* __restrict__ theta, float* __restrict__ cs) {
    int b = threadIdx.x;
    if (b < 4) {
        float s, c;
        sincosf(theta[b], &s, &c);
        cs[b]     = c;   // cos, b=0..3
        cs[4 + b] = s;   // sin, b=0..3
    }
}

__global__ __launch_bounds__(256)
void CPHASE_34583076667990_kernel(const v4f* __restrict__ re_in,
                                  const v4f* __restrict__ im_in,
                                  const v4f* __restrict__ cs,
                                  v4f* __restrict__ out_re,
                                  v4f* __restrict__ out_im) {
    unsigned t = blockIdx.x * blockDim.x + threadIdx.x;  // [0, N_VEC)
    v4f re = __builtin_nontemporal_load(&re_in[t]);
    v4f im = __builtin_nontemporal_load(&im_in[t]);
    if (t >= PHASE_START) {                 // wave-uniform (boundary is block-aligned)
        const v4f c = cs[0];                // 8 floats total, L2-resident broadcast
        const v4f s = cs[1];
        v4f nre = re * c - im * s;
        v4f nim = re * s + im * c;
        re = nre;
        im = nim;
    }
    __builtin_nontemporal_store(re, &out_re[t]);
    __builtin_nontemporal_store(im, &out_im[t]);
}

extern "C" void kernel_launch(void* const* d_in, const int* in_sizes, int n_in,
                              void* d_out, int out_size, void* d_ws, size_t ws_size,
                              hipStream_t stream) {
    const float* re    = (const float*)d_in[0];
    const float* im    = (const float*)d_in[1];
    const float* theta = (const float*)d_in[2];
    float* out = (float*)d_out;
    float* cs  = (float*)d_ws;   // 8 floats: [cos0..3, sin0..3]

    cphase_setup<<<1, 64, 0, stream>>>(theta, cs);

    dim3 block(256);
    dim3 grid(N_VEC / 256);  // 2^22 / 256 = 16384 blocks
    CPHASE_34583076667990_kernel<<<grid, block, 0, stream>>>(
        (const v4f*)re, (const v4f*)im, (const v4f*)cs,
        (v4f*)out, (v4f*)(out + N_ELEMS));
}

// Round 4
// 223.497 us; speedup vs baseline: 1.0580x; 1.0091x over previous
//
#include <hip/hip_runtime.h>
#include <math.h>

// CPHASE on qubits (0,1) of a 22-qubit state, batch B=4 (innermost axis).
// Flat amplitude index: (((q0*2+q1) * 2^20 + rest) * 4 + b)  -> q01 = top 2 bits.
// Only the q01==3 quarter gets phase exp(i*theta[b]); the rest is a copy.
//
// Single fused streaming kernel: phase factors computed per-thread with the
// NATIVE sin/cos intrinsics (v_sin_f32/v_cos_f32 — 2 trans ops, no ocml
// slow-path bloat; theta ~ N(0,1) so precision ~1e-6 vs 0.108 threshold).
// VALU is ~5% busy, so the redundant transcendentals are free; this removes
// the setup-kernel launch and the d_ws round-trip.
//
// Clang native vectors (ext_vector_type) — HIP's float4 class is rejected by
// __builtin_nontemporal_load/store.

typedef float v4f __attribute__((ext_vector_type(4)));

#define N_ELEMS (1u << 24)          // 2^22 amplitudes * 4 batch
#define N_VEC   (N_ELEMS / 4u)      // one v4f (all 4 batch lanes) per thread
#define PHASE_START (3u << 20)      // first v4f index with q01==3 (block-aligned)

__global__ __launch_bounds__(256)
void CPHASE_34583076667990_kernel(const v4f* __restrict__ re_in,
                                  const v4f* __restrict__ im_in,
                                  const float* __restrict__ theta,
                                  v4f* __restrict__ out_re,
                                  v4f* __restrict__ out_im) {
    unsigned t = blockIdx.x * blockDim.x + threadIdx.x;  // [0, N_VEC)
    v4f re = __builtin_nontemporal_load(&re_in[t]);
    v4f im = __builtin_nontemporal_load(&im_in[t]);
    if (t >= PHASE_START) {                 // wave-uniform (boundary block-aligned)
        v4f c, s;
        float sv, cv;
        __sincosf(theta[0], &sv, &cv); c.x = cv; s.x = sv;
        __sincosf(theta[1], &sv, &cv); c.y = cv; s.y = sv;
        __sincosf(theta[2], &sv, &cv); c.z = cv; s.z = sv;
        __sincosf(theta[3], &sv, &cv); c.w = cv; s.w = sv;
        v4f nre = re * c - im * s;
        v4f nim = re * s + im * c;
        re = nre;
        im = nim;
    }
    __builtin_nontemporal_store(re, &out_re[t]);
    __builtin_nontemporal_store(im, &out_im[t]);
}

extern "C" void kernel_launch(void* const* d_in, const int* in_sizes, int n_in,
                              void* d_out, int out_size, void* d_ws, size_t ws_size,
                              hipStream_t stream) {
    const float* re    = (const float*)d_in[0];
    const float* im    = (const float*)d_in[1];
    const float* theta = (const float*)d_in[2];
    float* out = (float*)d_out;

    dim3 block(256);
    dim3 grid(N_VEC / 256);  // 2^22 / 256 = 16384 blocks
    CPHASE_34583076667990_kernel<<<grid, block, 0, stream>>>(
        (const v4f*)re, (const v4f*)im, theta,
        (v4f*)out, (v4f*)(out + N_ELEMS));
}